// Round 14
// baseline (668.776 us; speedup 1.0000x reference)
//
#include <hip/hip_runtime.h>
#include <hip/hip_bf16.h>

// GraphTransformerLayer on MI355X — round 14.
// vs round 13 (three neutral latency rounds -> barrier-phase serialization is
// the residual cost): edge_kernel restructured to 1024 threads / 256 edges
// with DOUBLE-BUFFERED sW (2x32KB). Writes target the idle buffer, so the
// pre-write barrier vanishes: 6 barriers/block instead of 12, staging loads
// fly under the previous phase's compute, prologue amortized 2x. LDS 132KB ->
// 1 block/CU x 16 waves = 4 waves/SIMD (>= r13's occupancy). The exact x0.25
// score scale is folded into We at prep (power-of-2, bit-identical).
// node/qkv identical to r13.

constexpr int N_ = 40000;
constexpr int E_ = 640000;

typedef __attribute__((ext_vector_type(8))) short bf16x8;
typedef __attribute__((ext_vector_type(4))) float f32x4;

__device__ inline short f2bf(float f) {
    union { __hip_bfloat16 b; short s; } u;
    u.b = __float2bfloat16(f);
    return u.s;
}
__device__ inline float bf2f(unsigned short u) {
    union { unsigned u; float f; } v; v.u = ((unsigned)u) << 16; return v.f;
}
__device__ inline unsigned packbf2(float a, float b) {
    return (unsigned)(unsigned short)f2bf(a) |
           ((unsigned)(unsigned short)f2bf(b) << 16);
}

__device__ inline f32x4 mfma16(bf16x8 a, bf16x8 b, f32x4 c) {
    return __builtin_amdgcn_mfma_f32_16x16x32_bf16(a, b, c, 0, 0, 0);
}

__device__ inline float red16(float v) {
    v += __shfl_xor(v, 1);
    v += __shfl_xor(v, 2);
    v += __shfl_xor(v, 4);
    v += __shfl_xor(v, 8);
    return v;
}

template<int KSTEPS, int LDA>
__device__ inline void load_af(const short* sA, int row, int g, bf16x8* af) {
#pragma unroll
    for (int ks = 0; ks < KSTEPS; ++ks)
        af[ks] = *(const bf16x8*)(sA + row * LDA + ks * 32 + g * 8);
}

// B-fragments from fragment-ordered sW: block (n*4+ks) is 1024B, lane reads
// its own contiguous 16B slot. Conflict-free.
template<int KSTEPS>
__device__ inline f32x4 gemm_tileF(const bf16x8* af, const short* sW,
                                   int n, int lane, f32x4 acc) {
#pragma unroll
    for (int ks = 0; ks < KSTEPS; ++ks)
        acc = mfma16(af[ks],
                     *(const bf16x8*)(sW + ((n * 4 + ks) * 64 + lane) * 8), acc);
    return acc;
}

// Weight tile (32KB) global->reg / reg->LDS, lane-linear (conflict-free).
template<int NT>
__device__ inline void loadW(const short* __restrict__ Wsrc, int tid,
                             bf16x8* r) {
    constexpr int P = 2048 / NT;
#pragma unroll
    for (int p = 0; p < P; ++p)
        r[p] = *(const bf16x8*)(Wsrc + (tid + p * NT) * 8);
}
template<int NT>
__device__ inline void writeW(short* sW, int tid, const bf16x8* r) {
    constexpr int P = 2048 / NT;
#pragma unroll
    for (int p = 0; p < P; ++p)
        *(bf16x8*)(sW + (tid + p * NT) * 8) = r[p];
}
template<int NT>
__device__ inline void stageWX(const short* __restrict__ Wsrc, short* sW,
                               int tid) {
    bf16x8 t[2048 / NT];
    loadW<NT>(Wsrc, tid, t);
    writeW<NT>(sW, tid, t);
}

// Stage one wave's 16 rows of a [*,128] f32 matrix into LDS as bf16.
__device__ inline void stage64(const float* __restrict__ gsrc, short* sA,
                               int lane, int rowB) {
    int rr = rowB + (lane >> 2);
    int c0 = (lane & 3) * 32;
    const float* gp = gsrc + (size_t)rr * 128 + c0;
    short* dp = sA + rr * 136 + c0;
#pragma unroll
    for (int p = 0; p < 4; ++p) {
        float4 x = *(const float4*)(gp + p * 8);
        float4 y = *(const float4*)(gp + p * 8 + 4);
        bf16x8 v;
        v[0] = f2bf(x.x); v[1] = f2bf(x.y); v[2] = f2bf(x.z); v[3] = f2bf(x.w);
        v[4] = f2bf(y.x); v[5] = f2bf(y.y); v[6] = f2bf(y.z); v[7] = f2bf(y.w);
        *(bf16x8*)(dp + p * 8) = v;
    }
}

// x1 = LN(eres + A@W + bias); A bf16 in sA, W fragment-ordered in sW.
__device__ inline void proj_ln(short* sA, const f32x4* eres, const short* sW,
                               const float* __restrict__ bias,
                               const float* __restrict__ gma,
                               const float* __restrict__ beta,
                               int rowB, int c, int g, int lane, f32x4* x1v) {
    bf16x8 af[4];
    load_af<4, 136>(sA, rowB + c, g, af);
    float sx[4] = {0, 0, 0, 0}, sxx[4] = {0, 0, 0, 0};
#pragma unroll
    for (int n = 0; n < 8; ++n) {
        f32x4 a = gemm_tileF<4>(af, sW, n, lane, f32x4{0.f, 0.f, 0.f, 0.f});
        const int col = n * 16 + c;
        float bo = bias[col];
#pragma unroll
        for (int r = 0; r < 4; ++r) {
            float xv = a[r] + bo + eres[n][r];
            a[r] = xv; sx[r] += xv; sxx[r] += xv * xv;
        }
        x1v[n] = a;
    }
    float mean[4], inv[4];
#pragma unroll
    for (int r = 0; r < 4; ++r) {
        float s = red16(sx[r]), s2 = red16(sxx[r]);
        mean[r] = s * 0.0078125f;
        float var = s2 * 0.0078125f - mean[r] * mean[r];
        inv[r] = rsqrtf(var + 1e-5f);
    }
#pragma unroll
    for (int n = 0; n < 8; ++n) {
        const int col = n * 16 + c;
        float gg = gma[col], bb = beta[col];
#pragma unroll
        for (int r = 0; r < 4; ++r) {
            float v1 = (x1v[n][r] - mean[r]) * inv[r] * gg + bb;
            x1v[n][r] = v1;
            sA[(rowB + g * 4 + r) * 136 + col] = f2bf(v1);
        }
    }
}

// out = LN(x1 + relu(x1@W1 + b1)@W2 + b2); W1/W2 staged in 32KB halves.
// (single-buffer r8 form — used by node_kernel only)
template<int NT>
__device__ inline void ffn_lnS(short* sA, short* sW,
                               const short* __restrict__ W1t,
                               const float* __restrict__ b1,
                               const short* __restrict__ W2t,
                               const float* __restrict__ b2,
                               const float* __restrict__ gma,
                               const float* __restrict__ beta,
                               int rowB, int c, int g, int lane, int tid,
                               f32x4* x1v, float* __restrict__ outp, int tb) {
    bf16x8 af[4];
    load_af<4, 136>(sA, rowB + c, g, af);
    bf16x8 wreg[2048 / NT];
    loadW<NT>(W1t, tid, wreg);
#pragma unroll
    for (int half = 0; half < 2; ++half) {
        __syncthreads();                     // prior sW consumers done
        writeW<NT>(sW, tid, wreg);
        loadW<NT>(W2t + half * 16384, tid, wreg);    // prefetch W2 half
        __syncthreads();
#pragma unroll
        for (int n2 = 0; n2 < 8; ++n2) {
            f32x4 a3 = gemm_tileF<4>(af, sW, n2, lane,
                                     f32x4{0.f, 0.f, 0.f, 0.f});
            const int col2 = half * 128 + n2 * 16 + c;
            float bb = b1[col2];
#pragma unroll
            for (int r = 0; r < 4; ++r)
                sA[(rowB + g * 4 + r) * 136 + n2 * 16 + c] =
                    f2bf(fmaxf(a3[r] + bb, 0.f));
        }
        bf16x8 a4[4];
        load_af<4, 136>(sA, rowB + c, g, a4);
        __syncthreads();
        writeW<NT>(sW, tid, wreg);
        if (half == 0) loadW<NT>(W1t + 16384, tid, wreg);  // prefetch W1 h1
        __syncthreads();
#pragma unroll
        for (int n = 0; n < 8; ++n)
            x1v[n] = gemm_tileF<4>(a4, sW, n, lane, x1v[n]);
    }
    float ty[4] = {0, 0, 0, 0}, tyy[4] = {0, 0, 0, 0};
#pragma unroll
    for (int n = 0; n < 8; ++n) {
        const int col = n * 16 + c;
        float bb = b2[col];
#pragma unroll
        for (int r = 0; r < 4; ++r) {
            float xv = x1v[n][r] + bb;
            x1v[n][r] = xv; ty[r] += xv; tyy[r] += xv * xv;
        }
    }
    float mean[4], inv[4];
#pragma unroll
    for (int r = 0; r < 4; ++r) {
        float s = red16(ty[r]), s2 = red16(tyy[r]);
        mean[r] = s * 0.0078125f;
        float var = s2 * 0.0078125f - mean[r] * mean[r];
        inv[r] = rsqrtf(var + 1e-5f);
    }
#pragma unroll
    for (int n = 0; n < 8; ++n) {
        const int col = n * 16 + c;
        float gg = gma[col], bb = beta[col];
#pragma unroll
        for (int r = 0; r < 4; ++r)
            outp[(size_t)(tb + rowB + g * 4 + r) * 128 + col] =
                (x1v[n][r] - mean[r]) * inv[r] * gg + bb;
    }
}

// ---------------------------------------------------------------- prep
// Emit weights in MFMA fragment order; We (m==3) pre-scaled by 0.25 (exact).
__global__ void prep_weights(
    const float* __restrict__ WQ, const float* __restrict__ WK,
    const float* __restrict__ WV, const float* __restrict__ We,
    const float* __restrict__ WOh, const float* __restrict__ WOe,
    const float* __restrict__ Wh1, const float* __restrict__ Wh2,
    const float* __restrict__ We1, const float* __restrict__ We2,
    short* __restrict__ out) {
    int i = blockIdx.x * 256 + threadIdx.x;
    if (i < 98304) {
        int m = i >> 14, r = i & 16383;
        const float* W = m == 0 ? WQ : m == 1 ? WK : m == 2 ? WV
                        : m == 3 ? We : m == 4 ? WOh : WOe;
        int blk = r >> 9, l = (r >> 3) & 63, j = r & 7;
        int n = blk >> 2, ks = blk & 3;
        int col = n * 16 + (l & 15);
        int k = ks * 32 + (l >> 4) * 8 + j;
        float v = W[k * 128 + col];
        if (m == 3) v *= 0.25f;                    // fold score scale (exact)
        out[i] = f2bf(v);
    } else if (i < 229376) {
        int j2 = i - 98304;
        int m = j2 >> 15, r = j2 & 32767;
        int half = r >> 14, q = r & 16383;
        int blk = q >> 9, l = (q >> 3) & 63, j = q & 7;
        int n = blk >> 2, ks = blk & 3;
        if (m == 0 || m == 2) {                    // W1-type [128][256]
            const float* W = (m == 0) ? Wh1 : We1;
            int col2 = half * 128 + n * 16 + (l & 15);
            int k = ks * 32 + (l >> 4) * 8 + j;
            out[i] = f2bf(W[k * 256 + col2]);
        } else {                                   // W2-type [256][128]
            const float* W = (m == 1) ? Wh2 : We2;
            int col = n * 16 + (l & 15);
            int k = half * 128 + ks * 32 + (l >> 4) * 8 + j;
            out[i] = f2bf(W[k * 128 + col]);
        }
    }
}

// ---------------------------------------------------------------- CSR build
__global__ void hist_kernel(const int* __restrict__ dst, int* __restrict__ cnt) {
    int i = blockIdx.x * 256 + threadIdx.x;
    if (i < E_) atomicAdd(&cnt[dst[i]], 1);
}

__global__ void __launch_bounds__(1024) scan_kernel(const int* __restrict__ cnt,
                                                    int* __restrict__ off) {
    __shared__ int part[1024];
    int t = threadIdx.x;
    int base = t * 40;
    int s = 0;
    if (base < N_) {
        int end = min(base + 40, N_);
        for (int i = base; i < end; ++i) s += cnt[i];
    }
    part[t] = s;
    __syncthreads();
    for (int d = 1; d < 1024; d <<= 1) {
        int v = (t >= d) ? part[t - d] : 0;
        __syncthreads();
        part[t] += v;
        __syncthreads();
    }
    int prefix = (t == 0) ? 0 : part[t - 1];
    if (base < N_) {
        int end = min(base + 40, N_);
        int run = prefix;
        for (int i = base; i < end; ++i) { off[i] = run; run += cnt[i]; }
    }
    if (t == 1023) off[N_] = part[1023];
}

__global__ void scatter_kernel(const int* __restrict__ src,
                               const int* __restrict__ dst,
                               const int* __restrict__ off,
                               int* __restrict__ cursor,
                               int* __restrict__ slotOf,
                               int* __restrict__ csr_src) {
    int i = blockIdx.x * 256 + threadIdx.x;
    if (i < E_) {
        int d = dst[i];
        int s = off[d] + atomicAdd(&cursor[d], 1);
        slotOf[i] = s;
        csr_src[s] = src[i];
    }
}

// ---------------------------------------------------------------- QKV (bf16 out)
__global__ void __launch_bounds__(256) qkv_kernel(
    const float* __restrict__ hsrc, const short* __restrict__ Wt3,
    unsigned short* __restrict__ Qo, unsigned short* __restrict__ Ko,
    unsigned short* __restrict__ Vo) {
    __shared__ __align__(16) short sA[64 * 136];
    __shared__ __align__(16) short sW[128 * 128];
    const int tid = threadIdx.x;
    const int tb = blockIdx.x * 64;
    const int lane = tid & 63, wave = tid >> 6;
    const int c = lane & 15, g = lane >> 4;
    const int rowB = wave * 16;

    stage64(hsrc + (size_t)tb * 128, sA, lane, rowB);
    bf16x8 af[4];
    load_af<4, 136>(sA, rowB + c, g, af);

    unsigned short* outs[3] = {Qo, Ko, Vo};
#pragma unroll
    for (int w = 0; w < 3; ++w) {
        __syncthreads();
        stageWX<256>(Wt3 + w * 16384, sW, tid);
        __syncthreads();
        unsigned short* op = outs[w];
#pragma unroll
        for (int n = 0; n < 8; ++n) {
            f32x4 a = gemm_tileF<4>(af, sW, n, lane, f32x4{0.f, 0.f, 0.f, 0.f});
            const int col = n * 16 + c;
#pragma unroll
            for (int r = 0; r < 4; ++r)
                op[(size_t)(tb + rowB + g * 4 + r) * 128 + col] =
                    (unsigned short)f2bf(a[r]);
        }
    }
}

// ---------------------------------------------------------------- edges
// 1024 threads, 16 waves x 16 edges, 256 edges/block; double-buffered sW.
__global__ void __launch_bounds__(1024, 4) edge_kernel(
    const float* __restrict__ e, const int* __restrict__ src,
    const int* __restrict__ dst, const int* __restrict__ slotOf,
    const unsigned short* __restrict__ Qb, const unsigned short* __restrict__ Kb,
    float* __restrict__ sexpS,
    const short* __restrict__ Wet, const short* __restrict__ WOet,
    const short* __restrict__ We1t, const short* __restrict__ We2t,
    const float* __restrict__ bOe,
    const float* __restrict__ g1e, const float* __restrict__ b1e,
    const float* __restrict__ be1, const float* __restrict__ be2,
    const float* __restrict__ g2e, const float* __restrict__ b2e,
    float* __restrict__ e2out) {
    __shared__ __align__(16) short sA[256 * 136];     // 69.6 KB
    __shared__ __align__(16) short sW0[128 * 128];    // 32 KB
    __shared__ __align__(16) short sW1[128 * 128];    // 32 KB
    const int tid = threadIdx.x;
    const int tb = blockIdx.x * 256;
    const int lane = tid & 63, wave = tid >> 6;       // wave 0..15
    const int c = lane & 15, g = lane >> 4;
    const int rowB = wave * 16;

    // indices first (oldest VMEM)
    int pre = 0;
    {
        int li = lane & 15;
        if (lane < 16)       pre = src[tb + rowB + li];
        else if (lane < 32)  pre = dst[tb + rowB + li];
        else if (lane < 48)  pre = slotOf[tb + rowB + li];
    }

    bf16x8 wreg[2];
    loadW<1024>(Wet, tid, wreg);
    stage64(e + (size_t)tb * 128, sA, lane, rowB);

    // residual e in registers (acc layout)
    f32x4 eres[8];
#pragma unroll
    for (int n = 0; n < 8; ++n)
#pragma unroll
        for (int r = 0; r < 4; ++r)
            eres[n][r] = e[(size_t)(tb + rowB + g * 4 + r) * 128 + n * 16 + c];

    // all 16 K + 16 Q gathers issued before the barrier (drained at it)
    unsigned krg[16], qrg[16];
#pragma unroll
    for (int k = 0; k < 16; ++k) {
        int sI = __shfl(pre, k);
        krg[k] = *(const unsigned*)(Kb + (size_t)sI * 128 + 2 * lane);
    }
#pragma unroll
    for (int k = 0; k < 16; ++k) {
        int dI = __shfl(pre, 16 + k);
        qrg[k] = *(const unsigned*)(Qb + (size_t)dI * 128 + 2 * lane);
    }

    writeW<1024>(sW0, tid, wreg);    // waits Wet only
    __syncthreads();                 // B1: sA + sW0 ready, all VMEM drained

    loadW<1024>(WOet, tid, wreg);    // flies under GEMM1 + score

    // GEMM1: pe = e @ (We/4) -> stash bf16 into sA (wave-private rows)
    bf16x8 af[4];
    load_af<4, 136>(sA, rowB + c, g, af);
#pragma unroll
    for (int n = 0; n < 8; ++n) {
        f32x4 p = gemm_tileF<4>(af, sW0, n, lane, f32x4{0.f, 0.f, 0.f, 0.f});
#pragma unroll
        for (int r = 0; r < 4; ++r)
            sA[(rowB + g * 4 + r) * 136 + n * 16 + c] = f2bf(p[r]);
    }

    // ---- score phase (0.25 folded into We at prep)
    const int head = lane >> 3;
#pragma unroll
    for (int i = 0; i < 16; ++i) {
        const int row = rowB + i;
        const int slot = __shfl(pre, 32 + i);   // full-exec shfl
        unsigned kk = krg[i], qq = qrg[i];
        unsigned pp = *(const unsigned*)(sA + row * 136 + 2 * lane);
        float sc0 = bf2f((unsigned short)kk) * bf2f((unsigned short)qq) *
                    bf2f((unsigned short)pp);
        float sc1 = bf2f((unsigned short)(kk >> 16)) *
                    bf2f((unsigned short)(qq >> 16)) *
                    bf2f((unsigned short)(pp >> 16));
        *(unsigned*)(sA + row * 136 + 2 * lane) = packbf2(sc0, sc1);
        float s = sc0 + sc1;
        s += __shfl_xor(s, 1);
        s += __shfl_xor(s, 2);
        s += __shfl_xor(s, 4);
        s = fminf(5.f, fmaxf(-5.f, s));
        if ((lane & 7) == 0)
            sexpS[(size_t)slot * 8 + head] = __expf(s);
    }

    writeW<1024>(sW1, tid, wreg);    // WOe (waits its own loads only)
    __syncthreads();                 // B2

    loadW<1024>(We1t, tid, wreg);    // W1 h0
    f32x4 x1v[8];
    proj_ln(sA, eres, sW1, bOe, g1e, b1e, rowB, c, g, lane, x1v);
    writeW<1024>(sW0, tid, wreg);    // W1 h0
    __syncthreads();                 // B3

    bf16x8 af2[4];
    load_af<4, 136>(sA, rowB + c, g, af2);   // x1 fragments
    loadW<1024>(We2t, tid, wreg);            // W2 k0
    // u half0 = relu(x1 @ W1h0 + be1[0:128]) -> sA
#pragma unroll
    for (int n2 = 0; n2 < 8; ++n2) {
        f32x4 a3 = gemm_tileF<4>(af2, sW0, n2, lane, f32x4{0.f, 0.f, 0.f, 0.f});
        float bb = be1[n2 * 16 + c];
#pragma unroll
        for (int r = 0; r < 4; ++r)
            sA[(rowB + g * 4 + r) * 136 + n2 * 16 + c] =
                f2bf(fmaxf(a3[r] + bb, 0.f));
    }
    bf16x8 a40[4];
    load_af<4, 136>(sA, rowB + c, g, a40);   // u0 (wave-private, in-order)
    writeW<1024>(sW1, tid, wreg);            // W2 k0
    __syncthreads();                          // B4

    loadW<1024>(We1t + 16384, tid, wreg);    // W1 h1
#pragma unroll
    for (int n = 0; n < 8; ++n)
        x1v[n] = gemm_tileF<4>(a40, sW1, n, lane, x1v[n]);   // += u0 @ W2k0
    writeW<1024>(sW0, tid, wreg);            // W1 h1
    __syncthreads();                          // B5

    loadW<1024>(We2t + 16384, tid, wreg);    // W2 k1
    // u half1 = relu(x1 @ W1h1 + be1[128:256]) -> sA
#pragma unroll
    for (int n2 = 0; n2 < 8; ++n2) {
        f32x4 a3 = gemm_tileF<4>(af2, sW0, n2, lane, f32x4{0.f, 0.f, 0.f, 0.f});
        float bb = be1[128 + n2 * 16 + c];
#pragma unroll
        for (int r = 0; r < 4; ++r)
            sA[(rowB + g * 4 + r) * 136 + n2 * 16 + c] =
                f2bf(fmaxf(a3[r] + bb, 0.f));
    }
    bf16x8 a41[4];
    load_af<4, 136>(sA, rowB + c, g, a41);
    writeW<1024>(sW1, tid, wreg);            // W2 k1
    __syncthreads();                          // B6

#pragma unroll
    for (int n = 0; n < 8; ++n)
        x1v[n] = gemm_tileF<4>(a41, sW1, n, lane, x1v[n]);   // += u1 @ W2k1

    // LN2 + store
    float ty[4] = {0, 0, 0, 0}, tyy[4] = {0, 0, 0, 0};
#pragma unroll
    for (int n = 0; n < 8; ++n) {
        float bb = be2[n * 16 + c];
#pragma unroll
        for (int r = 0; r < 4; ++r) {
            float xv = x1v[n][r] + bb;
            x1v[n][r] = xv; ty[r] += xv; tyy[r] += xv * xv;
        }
    }
    float mean[4], inv[4];
#pragma unroll
    for (int r = 0; r < 4; ++r) {
        float s = red16(ty[r]), s2 = red16(tyy[r]);
        mean[r] = s * 0.0078125f;
        float var = s2 * 0.0078125f - mean[r] * mean[r];
        inv[r] = rsqrtf(var + 1e-5f);
    }
#pragma unroll
    for (int n = 0; n < 8; ++n) {
        const int col = n * 16 + c;
        float gg = g2e[col], bb = b2e[col];
#pragma unroll
        for (int r = 0; r < 4; ++r)
            e2out[(size_t)(tb + rowB + g * 4 + r) * 128 + col] =
                (x1v[n][r] - mean[r]) * inv[r] * gg + bb;
    }
}

// ---------------------------------------------------------------- nodes
__global__ void __launch_bounds__(256) node_kernel(
    const float* __restrict__ h, const unsigned short* __restrict__ Vb,
    const float* __restrict__ sexpS,
    const int* __restrict__ off, const int* __restrict__ csr_src,
    const short* __restrict__ WOht, const short* __restrict__ Wh1t,
    const short* __restrict__ Wh2t,
    const float* __restrict__ bOh,
    const float* __restrict__ g1h, const float* __restrict__ b1h,
    const float* __restrict__ bh1, const float* __restrict__ bh2,
    const float* __restrict__ g2h, const float* __restrict__ b2h,
    float* __restrict__ h2out) {
    __shared__ __align__(16) short sA[64 * 136];
    __shared__ __align__(16) short sW[128 * 128];
    const int tid = threadIdx.x;
    const int tb = blockIdx.x * 64;
    const int lane = tid & 63, wave = tid >> 6;
    const int c = lane & 15, g = lane >> 4;
    const int rowB = wave * 16;
    const int head = lane >> 3;

    stageWX<256>(WOht, sW, tid);     // overlapped with the pull phase

    // residual h in registers (acc layout)
    f32x4 hres[8];
#pragma unroll
    for (int n = 0; n < 8; ++n)
#pragma unroll
        for (int r = 0; r < 4; ++r)
            hres[n][r] = h[(size_t)(tb + rowB + g * 4 + r) * 128 + n * 16 + c];

    // preload CSR offsets for this wave's 16 nodes (+1)
    int offv = (lane < 17) ? off[tb + rowB + lane] : 0;

    // phase A: pull-reduce h_attn, batched 8-wide
    for (int i = 0; i < 16; ++i) {
        const int b0 = __shfl(offv, i), b1 = __shfl(offv, i + 1);
        float a0 = 0.f, a1 = 0.f, zz = 0.f;
        for (int j0 = b0; j0 < b1; j0 += 8) {
            int jj = j0 + (lane & 7);
            int ci = (jj < b1) ? csr_src[jj] : 0;
            unsigned vv[8]; float sv[8];
#pragma unroll
            for (int k = 0; k < 8; ++k) {
                bool ok = (j0 + k) < b1;
                int cs = __shfl(ci, k);
                vv[k] = ok ? *(const unsigned*)(Vb + (size_t)cs * 128 + 2 * lane)
                           : 0u;
                sv[k] = ok ? sexpS[(size_t)(j0 + k) * 8 + head] : 0.f;
            }
#pragma unroll
            for (int k = 0; k < 8; ++k) {
                a0 += bf2f((unsigned short)vv[k]) * sv[k];
                a1 += bf2f((unsigned short)(vv[k] >> 16)) * sv[k];
                zz += sv[k];
            }
        }
        float iz = 1.f / (zz + 1e-6f);
        *(unsigned*)(sA + (rowB + i) * 136 + 2 * lane) = packbf2(a0 * iz, a1 * iz);
    }

    __syncthreads();     // sW(WOh) staged + all sA writes visible

    f32x4 x1v[8];
    proj_ln(sA, hres, sW, bOh, g1h, b1h, rowB, c, g, lane, x1v);
    ffn_lnS<256>(sA, sW, Wh1t, bh1, Wh2t, bh2, g2h, b2h,
                 rowB, c, g, lane, tid, x1v, h2out, tb);
}

// ---------------------------------------------------------------- launch
extern "C" void kernel_launch(void* const* d_in, const int* in_sizes, int n_in,
                              void* d_out, int out_size, void* d_ws,
                              size_t ws_size, hipStream_t stream) {
    const float* h   = (const float*)d_in[0];
    const float* e   = (const float*)d_in[1];
    const int*   src = (const int*)d_in[2];
    const int*   dst = (const int*)d_in[3];
    const float* WQ  = (const float*)d_in[4];
    const float* WK  = (const float*)d_in[5];
    const float* WV  = (const float*)d_in[6];
    const float* We  = (const float*)d_in[7];
    const float* WOh = (const float*)d_in[8];
    const float* bOh = (const float*)d_in[9];
    const float* WOe = (const float*)d_in[10];
    const float* bOe = (const float*)d_in[11];
    const float* g1h = (const float*)d_in[12];
    const float* b1h = (const float*)d_in[13];
    const float* g1e = (const float*)d_in[14];
    const float* b1e = (const float*)d_in[15];
    const float* Wh1 = (const float*)d_in[16];
    const float* bh1 = (const float*)d_in[17];
    const float* Wh2 = (const float*)d_in[18];
    const float* bh2 = (const float*)d_in[19];
    const float* We1 = (const float*)d_in[20];
    const float* be1 = (const float*)d_in[21];
    const float* We2 = (const float*)d_in[22];
    const float* be2 = (const float*)d_in[23];
    const float* g2h = (const float*)d_in[24];
    const float* b2h = (const float*)d_in[25];
    const float* g2e = (const float*)d_in[26];
    const float* b2e = (const float*)d_in[27];

    unsigned short* Qb = (unsigned short*)d_ws;            // N*128 bf16
    unsigned short* Kb = Qb + (size_t)N_ * 128;
    unsigned short* Vb = Kb + (size_t)N_ * 128;
    float* sexpS = (float*)(Vb + (size_t)N_ * 128);        // E*8 (CSR slot order)
    int* cnt     = (int*)(sexpS + (size_t)E_ * 8);         // N
    int* cursor  = cnt + N_;                               // N
    int* off     = cursor + N_;                            // N+1 (pad to N+16)
    int* slotOf  = off + N_ + 16;                          // E
    int* csr_src = slotOf + E_;                            // E
    short* Wb    = (short*)(csr_src + E_);                 // bf16 weights (16B-aligned)

    float* h2out = (float*)d_out;
    float* e2out = h2out + (size_t)N_ * 128;

    prep_weights<<<896, 256, 0, stream>>>(WQ, WK, WV, We, WOh, WOe,
                                          Wh1, Wh2, We1, We2, Wb);
    hipMemsetAsync(cnt, 0, 2 * N_ * sizeof(int), stream);  // cnt + cursor
    hist_kernel<<<E_ / 256, 256, 0, stream>>>(dst, cnt);
    scan_kernel<<<1, 1024, 0, stream>>>(cnt, off);
    scatter_kernel<<<E_ / 256, 256, 0, stream>>>(src, dst, off, cursor,
                                                 slotOf, csr_src);
    qkv_kernel<<<N_ / 64, 256, 0, stream>>>(h, Wb, Qb, Kb, Vb);
    edge_kernel<<<E_ / 256, 1024, 0, stream>>>(
        e, src, dst, slotOf, Qb, Kb, sexpS,
        Wb + 3 * 16384, Wb + 5 * 16384,
        Wb + 98304 + 2 * 32768, Wb + 98304 + 3 * 32768,
        bOe, g1e, b1e, be1, be2, g2e, b2e, e2out);
    node_kernel<<<N_ / 64, 256, 0, stream>>>(
        h, Vb, sexpS, off, csr_src,
        Wb + 4 * 16384, Wb + 98304, Wb + 98304 + 32768,
        bOh, g1h, b1h, bh1, bh2, g2h, b2h, h2out);
}

// Round 15
// 488.380 us; speedup vs baseline: 1.3694x; 1.3694x over previous
//
#include <hip/hip_runtime.h>
#include <hip/hip_bf16.h>

// GraphTransformerLayer on MI355X — round 15.
// = round 11 exactly (best known-good, 497.6us; r14's 1024-thread double-buffer
//   spilled to scratch: VGPR=64 + WRITE 860MB -> reverted) + ONE safe change:
//   hist_kernel fused into qkv_kernel as extra blocks (disjoint ranges, no
//   shared state) — removes one serialized launch from the critical path.

constexpr int N_ = 40000;
constexpr int E_ = 640000;

typedef __attribute__((ext_vector_type(8))) short bf16x8;
typedef __attribute__((ext_vector_type(4))) float f32x4;

__device__ inline short f2bf(float f) {
    union { __hip_bfloat16 b; short s; } u;
    u.b = __float2bfloat16(f);
    return u.s;
}
__device__ inline float bf2f(unsigned short u) {
    union { unsigned u; float f; } v; v.u = ((unsigned)u) << 16; return v.f;
}
__device__ inline unsigned packbf2(float a, float b) {
    return (unsigned)(unsigned short)f2bf(a) |
           ((unsigned)(unsigned short)f2bf(b) << 16);
}

__device__ inline f32x4 mfma16(bf16x8 a, bf16x8 b, f32x4 c) {
    return __builtin_amdgcn_mfma_f32_16x16x32_bf16(a, b, c, 0, 0, 0);
}

__device__ inline float red16(float v) {
    v += __shfl_xor(v, 1);
    v += __shfl_xor(v, 2);
    v += __shfl_xor(v, 4);
    v += __shfl_xor(v, 8);
    return v;
}

template<int KSTEPS, int LDA>
__device__ inline void load_af(const short* sA, int row, int g, bf16x8* af) {
#pragma unroll
    for (int ks = 0; ks < KSTEPS; ++ks)
        af[ks] = *(const bf16x8*)(sA + row * LDA + ks * 32 + g * 8);
}

// B-fragments from fragment-ordered sW: block (n*4+ks) is 1024B, lane reads
// its own contiguous 16B slot. Conflict-free.
template<int KSTEPS>
__device__ inline f32x4 gemm_tileF(const bf16x8* af, const short* sW,
                                   int n, int lane, f32x4 acc) {
#pragma unroll
    for (int ks = 0; ks < KSTEPS; ++ks)
        acc = mfma16(af[ks],
                     *(const bf16x8*)(sW + ((n * 4 + ks) * 64 + lane) * 8), acc);
    return acc;
}

// Weight tile (32KB) global->reg / reg->LDS, lane-linear (conflict-free).
template<int NT>
__device__ inline void loadW(const short* __restrict__ Wsrc, int tid,
                             bf16x8* r) {
    constexpr int P = 2048 / NT;
#pragma unroll
    for (int p = 0; p < P; ++p)
        r[p] = *(const bf16x8*)(Wsrc + (tid + p * NT) * 8);
}
template<int NT>
__device__ inline void writeW(short* sW, int tid, const bf16x8* r) {
    constexpr int P = 2048 / NT;
#pragma unroll
    for (int p = 0; p < P; ++p)
        *(bf16x8*)(sW + (tid + p * NT) * 8) = r[p];
}
template<int NT>
__device__ inline void stageWX(const short* __restrict__ Wsrc, short* sW,
                               int tid) {
    bf16x8 t[2048 / NT];
    loadW<NT>(Wsrc, tid, t);
    writeW<NT>(sW, tid, t);
}

// Stage one wave's 16 rows of a [*,128] f32 matrix into LDS as bf16.
__device__ inline void stage64(const float* __restrict__ gsrc, short* sA,
                               int lane, int rowB) {
    int rr = rowB + (lane >> 2);
    int c0 = (lane & 3) * 32;
    const float* gp = gsrc + (size_t)rr * 128 + c0;
    short* dp = sA + rr * 136 + c0;
#pragma unroll
    for (int p = 0; p < 4; ++p) {
        float4 x = *(const float4*)(gp + p * 8);
        float4 y = *(const float4*)(gp + p * 8 + 4);
        bf16x8 v;
        v[0] = f2bf(x.x); v[1] = f2bf(x.y); v[2] = f2bf(x.z); v[3] = f2bf(x.w);
        v[4] = f2bf(y.x); v[5] = f2bf(y.y); v[6] = f2bf(y.z); v[7] = f2bf(y.w);
        *(bf16x8*)(dp + p * 8) = v;
    }
}

// x1 = LN(eres + A@W + bias); A bf16 in sA, W fragment-ordered in sW.
__device__ inline void proj_ln(short* sA, const f32x4* eres, const short* sW,
                               const float* __restrict__ bias,
                               const float* __restrict__ gma,
                               const float* __restrict__ beta,
                               int rowB, int c, int g, int lane, f32x4* x1v) {
    bf16x8 af[4];
    load_af<4, 136>(sA, rowB + c, g, af);
    float sx[4] = {0, 0, 0, 0}, sxx[4] = {0, 0, 0, 0};
#pragma unroll
    for (int n = 0; n < 8; ++n) {
        f32x4 a = gemm_tileF<4>(af, sW, n, lane, f32x4{0.f, 0.f, 0.f, 0.f});
        const int col = n * 16 + c;
        float bo = bias[col];
#pragma unroll
        for (int r = 0; r < 4; ++r) {
            float xv = a[r] + bo + eres[n][r];
            a[r] = xv; sx[r] += xv; sxx[r] += xv * xv;
        }
        x1v[n] = a;
    }
    float mean[4], inv[4];
#pragma unroll
    for (int r = 0; r < 4; ++r) {
        float s = red16(sx[r]), s2 = red16(sxx[r]);
        mean[r] = s * 0.0078125f;
        float var = s2 * 0.0078125f - mean[r] * mean[r];
        inv[r] = rsqrtf(var + 1e-5f);
    }
#pragma unroll
    for (int n = 0; n < 8; ++n) {
        const int col = n * 16 + c;
        float gg = gma[col], bb = beta[col];
#pragma unroll
        for (int r = 0; r < 4; ++r) {
            float v1 = (x1v[n][r] - mean[r]) * inv[r] * gg + bb;
            x1v[n][r] = v1;
            sA[(rowB + g * 4 + r) * 136 + col] = f2bf(v1);
        }
    }
}

// out = LN(x1 + relu(x1@W1 + b1)@W2 + b2); W1/W2 staged in 32KB halves.
// (r8 form: W1 h0 loaded at entry — consumed 2 barrier-phases later, and no
// newer global load is consumed in between, so the prefetch is vmcnt-safe.)
template<int NT>
__device__ inline void ffn_lnS(short* sA, short* sW,
                               const short* __restrict__ W1t,
                               const float* __restrict__ b1,
                               const short* __restrict__ W2t,
                               const float* __restrict__ b2,
                               const float* __restrict__ gma,
                               const float* __restrict__ beta,
                               int rowB, int c, int g, int lane, int tid,
                               f32x4* x1v, float* __restrict__ outp, int tb) {
    bf16x8 af[4];
    load_af<4, 136>(sA, rowB + c, g, af);
    bf16x8 wreg[2048 / NT];
    loadW<NT>(W1t, tid, wreg);
#pragma unroll
    for (int half = 0; half < 2; ++half) {
        __syncthreads();                     // prior sW consumers done
        writeW<NT>(sW, tid, wreg);
        loadW<NT>(W2t + half * 16384, tid, wreg);    // prefetch W2 half
        __syncthreads();
#pragma unroll
        for (int n2 = 0; n2 < 8; ++n2) {
            f32x4 a3 = gemm_tileF<4>(af, sW, n2, lane,
                                     f32x4{0.f, 0.f, 0.f, 0.f});
            const int col2 = half * 128 + n2 * 16 + c;
            float bb = b1[col2];
#pragma unroll
            for (int r = 0; r < 4; ++r)
                sA[(rowB + g * 4 + r) * 136 + n2 * 16 + c] =
                    f2bf(fmaxf(a3[r] + bb, 0.f));
        }
        bf16x8 a4[4];
        load_af<4, 136>(sA, rowB + c, g, a4);
        __syncthreads();
        writeW<NT>(sW, tid, wreg);
        if (half == 0) loadW<NT>(W1t + 16384, tid, wreg);  // prefetch W1 h1
        __syncthreads();
#pragma unroll
        for (int n = 0; n < 8; ++n)
            x1v[n] = gemm_tileF<4>(a4, sW, n, lane, x1v[n]);
    }
    float ty[4] = {0, 0, 0, 0}, tyy[4] = {0, 0, 0, 0};
#pragma unroll
    for (int n = 0; n < 8; ++n) {
        const int col = n * 16 + c;
        float bb = b2[col];
#pragma unroll
        for (int r = 0; r < 4; ++r) {
            float xv = x1v[n][r] + bb;
            x1v[n][r] = xv; ty[r] += xv; tyy[r] += xv * xv;
        }
    }
    float mean[4], inv[4];
#pragma unroll
    for (int r = 0; r < 4; ++r) {
        float s = red16(ty[r]), s2 = red16(tyy[r]);
        mean[r] = s * 0.0078125f;
        float var = s2 * 0.0078125f - mean[r] * mean[r];
        inv[r] = rsqrtf(var + 1e-5f);
    }
#pragma unroll
    for (int n = 0; n < 8; ++n) {
        const int col = n * 16 + c;
        float gg = gma[col], bb = beta[col];
#pragma unroll
        for (int r = 0; r < 4; ++r)
            outp[(size_t)(tb + rowB + g * 4 + r) * 128 + col] =
                (x1v[n][r] - mean[r]) * inv[r] * gg + bb;
    }
}

// ---------------------------------------------------------------- prep
// Emit weights in MFMA fragment order (see gemm_tileF).
__global__ void prep_weights(
    const float* __restrict__ WQ, const float* __restrict__ WK,
    const float* __restrict__ WV, const float* __restrict__ We,
    const float* __restrict__ WOh, const float* __restrict__ WOe,
    const float* __restrict__ Wh1, const float* __restrict__ Wh2,
    const float* __restrict__ We1, const float* __restrict__ We2,
    short* __restrict__ out) {
    int i = blockIdx.x * 256 + threadIdx.x;
    if (i < 98304) {
        int m = i >> 14, r = i & 16383;
        const float* W = m == 0 ? WQ : m == 1 ? WK : m == 2 ? WV
                        : m == 3 ? We : m == 4 ? WOh : WOe;
        int blk = r >> 9, l = (r >> 3) & 63, j = r & 7;
        int n = blk >> 2, ks = blk & 3;
        int col = n * 16 + (l & 15);
        int k = ks * 32 + (l >> 4) * 8 + j;
        out[i] = f2bf(W[k * 128 + col]);
    } else if (i < 229376) {
        int j2 = i - 98304;
        int m = j2 >> 15, r = j2 & 32767;
        int half = r >> 14, q = r & 16383;
        int blk = q >> 9, l = (q >> 3) & 63, j = q & 7;
        int n = blk >> 2, ks = blk & 3;
        if (m == 0 || m == 2) {                    // W1-type [128][256]
            const float* W = (m == 0) ? Wh1 : We1;
            int col2 = half * 128 + n * 16 + (l & 15);
            int k = ks * 32 + (l >> 4) * 8 + j;
            out[i] = f2bf(W[k * 256 + col2]);
        } else {                                   // W2-type [256][128]
            const float* W = (m == 1) ? Wh2 : We2;
            int col = n * 16 + (l & 15);
            int k = half * 128 + ks * 32 + (l >> 4) * 8 + j;
            out[i] = f2bf(W[k * 128 + col]);
        }
    }
}

// ---------------------------------------------------------------- CSR build
__global__ void __launch_bounds__(1024) scan_kernel(const int* __restrict__ cnt,
                                                    int* __restrict__ off) {
    __shared__ int part[1024];
    int t = threadIdx.x;
    int base = t * 40;
    int s = 0;
    if (base < N_) {
        int end = min(base + 40, N_);
        for (int i = base; i < end; ++i) s += cnt[i];
    }
    part[t] = s;
    __syncthreads();
    for (int d = 1; d < 1024; d <<= 1) {
        int v = (t >= d) ? part[t - d] : 0;
        __syncthreads();
        part[t] += v;
        __syncthreads();
    }
    int prefix = (t == 0) ? 0 : part[t - 1];
    if (base < N_) {
        int end = min(base + 40, N_);
        int run = prefix;
        for (int i = base; i < end; ++i) { off[i] = run; run += cnt[i]; }
    }
    if (t == 1023) off[N_] = part[1023];
}

__global__ void scatter_kernel(const int* __restrict__ src,
                               const int* __restrict__ dst,
                               const int* __restrict__ off,
                               int* __restrict__ cursor,
                               int* __restrict__ slotOf,
                               int* __restrict__ csr_src) {
    int i = blockIdx.x * 256 + threadIdx.x;
    if (i < E_) {
        int d = dst[i];
        int s = off[d] + atomicAdd(&cursor[d], 1);
        slotOf[i] = s;
        csr_src[s] = src[i];
    }
}

// ---------------------------------------------------------------- QKV + hist
// Blocks [0,625): QKV projections. Blocks [625,3125): dst histogram.
__global__ void __launch_bounds__(256) qkv_hist_kernel(
    const float* __restrict__ hsrc, const short* __restrict__ Wt3,
    unsigned short* __restrict__ Qo, unsigned short* __restrict__ Ko,
    unsigned short* __restrict__ Vo,
    const int* __restrict__ dst, int* __restrict__ cnt) {
    __shared__ __align__(16) short sA[64 * 136];
    __shared__ __align__(16) short sW[128 * 128];
    const int tid = threadIdx.x;

    if (blockIdx.x >= N_ / 64) {                   // histogram blocks
        int i = (blockIdx.x - N_ / 64) * 256 + tid;
        if (i < E_) atomicAdd(&cnt[dst[i]], 1);
        return;
    }

    const int tb = blockIdx.x * 64;
    const int lane = tid & 63, wave = tid >> 6;
    const int c = lane & 15, g = lane >> 4;
    const int rowB = wave * 16;

    stage64(hsrc + (size_t)tb * 128, sA, lane, rowB);
    bf16x8 af[4];
    load_af<4, 136>(sA, rowB + c, g, af);

    unsigned short* outs[3] = {Qo, Ko, Vo};
#pragma unroll
    for (int w = 0; w < 3; ++w) {
        __syncthreads();
        stageWX<256>(Wt3 + w * 16384, sW, tid);
        __syncthreads();
        unsigned short* op = outs[w];
#pragma unroll
        for (int n = 0; n < 8; ++n) {
            f32x4 a = gemm_tileF<4>(af, sW, n, lane, f32x4{0.f, 0.f, 0.f, 0.f});
            const int col = n * 16 + c;
#pragma unroll
            for (int r = 0; r < 4; ++r)
                op[(size_t)(tb + rowB + g * 4 + r) * 128 + col] =
                    (unsigned short)f2bf(a[r]);
        }
    }
}

// ---------------------------------------------------------------- edges
// 512 threads, 8 waves x 16 edges (M=16), 128 edges/block.
__global__ void __launch_bounds__(512) edge_kernel(
    const float* __restrict__ e, const int* __restrict__ src,
    const int* __restrict__ dst, const int* __restrict__ slotOf,
    const unsigned short* __restrict__ Qb, const unsigned short* __restrict__ Kb,
    float* __restrict__ sexpS,
    const short* __restrict__ Wet, const short* __restrict__ WOet,
    const short* __restrict__ We1t, const short* __restrict__ We2t,
    const float* __restrict__ bOe,
    const float* __restrict__ g1e, const float* __restrict__ b1e,
    const float* __restrict__ be1, const float* __restrict__ be2,
    const float* __restrict__ g2e, const float* __restrict__ b2e,
    float* __restrict__ e2out) {
    __shared__ __align__(16) short sA[128 * 136];  // e -> pe -> score -> x1 -> u
    __shared__ __align__(16) short sW[128 * 128];  // per-phase weight tile
    const int tid = threadIdx.x;
    const int tb = blockIdx.x * 128;
    const int lane = tid & 63, wave = tid >> 6;
    const int c = lane & 15, g = lane >> 4;
    const int rowB = wave * 16;

    stageWX<512>(Wet, sW, tid);
    stage64(e + (size_t)tb * 128, sA, lane, rowB);

    // preload this wave's 16 src / 16 dst / 16 slot indices (lane-partitioned)
    int pre = 0;
    {
        int li = lane & 15;
        if (lane < 16)       pre = src[tb + rowB + li];
        else if (lane < 32)  pre = dst[tb + rowB + li];
        else if (lane < 48)  pre = slotOf[tb + rowB + li];
    }

    // residual e in registers (acc layout), issued early
    f32x4 eres[8];
#pragma unroll
    for (int n = 0; n < 8; ++n)
#pragma unroll
        for (int r = 0; r < 4; ++r)
            eres[n][r] = e[(size_t)(tb + rowB + g * 4 + r) * 128 + n * 16 + c];

    // all 16 K + 16 Q gathers issued before the barrier (drained at it).
    unsigned krg[16], qrg[16];
#pragma unroll
    for (int k = 0; k < 16; ++k) {
        int sI = __shfl(pre, k);
        krg[k] = *(const unsigned*)(Kb + (size_t)sI * 128 + 2 * lane);
    }
#pragma unroll
    for (int k = 0; k < 16; ++k) {
        int dI = __shfl(pre, 16 + k);
        qrg[k] = *(const unsigned*)(Qb + (size_t)dI * 128 + 2 * lane);
    }

    __syncthreads();     // sW(We) ready; krg/qrg drained

    // GEMM1: pe = e @ We -> stash bf16 into sA (wave-private rows)
    bf16x8 af[4];
    load_af<4, 136>(sA, rowB + c, g, af);
#pragma unroll
    for (int n = 0; n < 8; ++n) {
        f32x4 p = gemm_tileF<4>(af, sW, n, lane, f32x4{0.f, 0.f, 0.f, 0.f});
#pragma unroll
        for (int r = 0; r < 4; ++r)
            sA[(rowB + g * 4 + r) * 136 + n * 16 + c] = f2bf(p[r]);
    }

    // ---- score phase: consume the prefetched gathers
    const int head = lane >> 3;
#pragma unroll
    for (int i = 0; i < 16; ++i) {
        const int row = rowB + i;
        const int slot = __shfl(pre, 32 + i);   // full-exec shfl
        unsigned kk = krg[i], qq = qrg[i];
        unsigned pp = *(const unsigned*)(sA + row * 136 + 2 * lane);
        float sc0 = bf2f((unsigned short)kk) * bf2f((unsigned short)qq) *
                    0.25f * bf2f((unsigned short)pp);
        float sc1 = bf2f((unsigned short)(kk >> 16)) *
                    bf2f((unsigned short)(qq >> 16)) * 0.25f *
                    bf2f((unsigned short)(pp >> 16));
        *(unsigned*)(sA + row * 136 + 2 * lane) = packbf2(sc0, sc1);
        float s = sc0 + sc1;
        s += __shfl_xor(s, 1);
        s += __shfl_xor(s, 2);
        s += __shfl_xor(s, 4);
        s = fminf(5.f, fmaxf(-5.f, s));
        if ((lane & 7) == 0)
            sexpS[(size_t)slot * 8 + head] = __expf(s);
    }

    __syncthreads();     // all waves done with sW(We)
    stageWX<512>(WOet, sW, tid);
    __syncthreads();

    f32x4 x1v[8];
    proj_ln(sA, eres, sW, bOe, g1e, b1e, rowB, c, g, lane, x1v);
    ffn_lnS<512>(sA, sW, We1t, be1, We2t, be2, g2e, b2e,
                 rowB, c, g, lane, tid, x1v, e2out, tb);
}

// ---------------------------------------------------------------- nodes
__global__ void __launch_bounds__(256) node_kernel(
    const float* __restrict__ h, const unsigned short* __restrict__ Vb,
    const float* __restrict__ sexpS,
    const int* __restrict__ off, const int* __restrict__ csr_src,
    const short* __restrict__ WOht, const short* __restrict__ Wh1t,
    const short* __restrict__ Wh2t,
    const float* __restrict__ bOh,
    const float* __restrict__ g1h, const float* __restrict__ b1h,
    const float* __restrict__ bh1, const float* __restrict__ bh2,
    const float* __restrict__ g2h, const float* __restrict__ b2h,
    float* __restrict__ h2out) {
    __shared__ __align__(16) short sA[64 * 136];
    __shared__ __align__(16) short sW[128 * 128];
    const int tid = threadIdx.x;
    const int tb = blockIdx.x * 64;
    const int lane = tid & 63, wave = tid >> 6;
    const int c = lane & 15, g = lane >> 4;
    const int rowB = wave * 16;
    const int head = lane >> 3;

    stageWX<256>(WOht, sW, tid);     // overlapped with the pull phase

    // residual h in registers (acc layout)
    f32x4 hres[8];
#pragma unroll
    for (int n = 0; n < 8; ++n)
#pragma unroll
        for (int r = 0; r < 4; ++r)
            hres[n][r] = h[(size_t)(tb + rowB + g * 4 + r) * 128 + n * 16 + c];

    // preload CSR offsets for this wave's 16 nodes (+1)
    int offv = (lane < 17) ? off[tb + rowB + lane] : 0;

    // phase A: pull-reduce h_attn, batched 8-wide
    for (int i = 0; i < 16; ++i) {
        const int b0 = __shfl(offv, i), b1 = __shfl(offv, i + 1);
        float a0 = 0.f, a1 = 0.f, zz = 0.f;
        for (int j0 = b0; j0 < b1; j0 += 8) {
            int jj = j0 + (lane & 7);
            int ci = (jj < b1) ? csr_src[jj] : 0;
            unsigned vv[8]; float sv[8];
#pragma unroll
            for (int k = 0; k < 8; ++k) {
                bool ok = (j0 + k) < b1;
                int cs = __shfl(ci, k);
                vv[k] = ok ? *(const unsigned*)(Vb + (size_t)cs * 128 + 2 * lane)
                           : 0u;
                sv[k] = ok ? sexpS[(size_t)(j0 + k) * 8 + head] : 0.f;
            }
#pragma unroll
            for (int k = 0; k < 8; ++k) {
                a0 += bf2f((unsigned short)vv[k]) * sv[k];
                a1 += bf2f((unsigned short)(vv[k] >> 16)) * sv[k];
                zz += sv[k];
            }
        }
        float iz = 1.f / (zz + 1e-6f);
        *(unsigned*)(sA + (rowB + i) * 136 + 2 * lane) = packbf2(a0 * iz, a1 * iz);
    }

    __syncthreads();     // sW(WOh) staged + all sA writes visible

    f32x4 x1v[8];
    proj_ln(sA, hres, sW, bOh, g1h, b1h, rowB, c, g, lane, x1v);
    ffn_lnS<256>(sA, sW, Wh1t, bh1, Wh2t, bh2, g2h, b2h,
                 rowB, c, g, lane, tid, x1v, h2out, tb);
}

// ---------------------------------------------------------------- launch
extern "C" void kernel_launch(void* const* d_in, const int* in_sizes, int n_in,
                              void* d_out, int out_size, void* d_ws,
                              size_t ws_size, hipStream_t stream) {
    const float* h   = (const float*)d_in[0];
    const float* e   = (const float*)d_in[1];
    const int*   src = (const int*)d_in[2];
    const int*   dst = (const int*)d_in[3];
    const float* WQ  = (const float*)d_in[4];
    const float* WK  = (const float*)d_in[5];
    const float* WV  = (const float*)d_in[6];
    const float* We  = (const float*)d_in[7];
    const float* WOh = (const float*)d_in[8];
    const float* bOh = (const float*)d_in[9];
    const float* WOe = (const float*)d_in[10];
    const float* bOe = (const float*)d_in[11];
    const float* g1h = (const float*)d_in[12];
    const float* b1h = (const float*)d_in[13];
    const float* g1e = (const float*)d_in[14];
    const float* b1e = (const float*)d_in[15];
    const float* Wh1 = (const float*)d_in[16];
    const float* bh1 = (const float*)d_in[17];
    const float* Wh2 = (const float*)d_in[18];
    const float* bh2 = (const float*)d_in[19];
    const float* We1 = (const float*)d_in[20];
    const float* be1 = (const float*)d_in[21];
    const float* We2 = (const float*)d_in[22];
    const float* be2 = (const float*)d_in[23];
    const float* g2h = (const float*)d_in[24];
    const float* b2h = (const float*)d_in[25];
    const float* g2e = (const float*)d_in[26];
    const float* b2e = (const float*)d_in[27];

    unsigned short* Qb = (unsigned short*)d_ws;            // N*128 bf16
    unsigned short* Kb = Qb + (size_t)N_ * 128;
    unsigned short* Vb = Kb + (size_t)N_ * 128;
    float* sexpS = (float*)(Vb + (size_t)N_ * 128);        // E*8 (CSR slot order)
    int* cnt     = (int*)(sexpS + (size_t)E_ * 8);         // N
    int* cursor  = cnt + N_;                               // N
    int* off     = cursor + N_;                            // N+1 (pad to N+16)
    int* slotOf  = off + N_ + 16;                          // E
    int* csr_src = slotOf + E_;                            // E
    short* Wb    = (short*)(csr_src + E_);                 // bf16 weights (16B-aligned)

    float* h2out = (float*)d_out;
    float* e2out = h2out + (size_t)N_ * 128;

    hipMemsetAsync(cnt, 0, 2 * N_ * sizeof(int), stream);  // cnt + cursor
    prep_weights<<<896, 256, 0, stream>>>(WQ, WK, WV, We, WOh, WOe,
                                          Wh1, Wh2, We1, We2, Wb);
    qkv_hist_kernel<<<N_ / 64 + E_ / 256, 256, 0, stream>>>(
        h, Wb, Qb, Kb, Vb, dst, cnt);
    scan_kernel<<<1, 1024, 0, stream>>>(cnt, off);
    scatter_kernel<<<E_ / 256, 256, 0, stream>>>(src, dst, off, cursor,
                                                 slotOf, csr_src);
    edge_kernel<<<E_ / 128, 512, 0, stream>>>(
        e, src, dst, slotOf, Qb, Kb, sexpS,
        Wb + 3 * 16384, Wb + 5 * 16384,
        Wb + 98304 + 2 * 32768, Wb + 98304 + 3 * 32768,
        bOe, g1e, b1e, be1, be2, g2e, b2e, e2out);
    node_kernel<<<N_ / 64, 256, 0, stream>>>(
        h, Vb, sexpS, off, csr_src,
        Wb + 4 * 16384, Wb + 98304, Wb + 98304 + 32768,
        bOh, g1h, b1h, bh1, bh2, g2h, b2h, h2out);
}

// Round 17
// 461.952 us; speedup vs baseline: 1.4477x; 1.0572x over previous
//
#include <hip/hip_runtime.h>
#include <hip/hip_bf16.h>

// GraphTransformerLayer on MI355X — round 17.
// = round 15 (known-good 488.4us) + scatter fused into edge_kernel via the
//   SAFE formulation: flat tid<128 scatter (each thread loads its own
//   src/dst, atomicAdd slot, writes csr_src) with slots passed through LDS
//   (sSlot + barrier) — zero cross-lane ops on predicated values (r16's
//   shfl-of-predicated-slotv formulation failed; r3/r12/r16 cluster there).

constexpr int N_ = 40000;
constexpr int E_ = 640000;

typedef __attribute__((ext_vector_type(8))) short bf16x8;
typedef __attribute__((ext_vector_type(4))) float f32x4;

__device__ inline short f2bf(float f) {
    union { __hip_bfloat16 b; short s; } u;
    u.b = __float2bfloat16(f);
    return u.s;
}
__device__ inline float bf2f(unsigned short u) {
    union { unsigned u; float f; } v; v.u = ((unsigned)u) << 16; return v.f;
}
__device__ inline unsigned packbf2(float a, float b) {
    return (unsigned)(unsigned short)f2bf(a) |
           ((unsigned)(unsigned short)f2bf(b) << 16);
}

__device__ inline f32x4 mfma16(bf16x8 a, bf16x8 b, f32x4 c) {
    return __builtin_amdgcn_mfma_f32_16x16x32_bf16(a, b, c, 0, 0, 0);
}

__device__ inline float red16(float v) {
    v += __shfl_xor(v, 1);
    v += __shfl_xor(v, 2);
    v += __shfl_xor(v, 4);
    v += __shfl_xor(v, 8);
    return v;
}

template<int KSTEPS, int LDA>
__device__ inline void load_af(const short* sA, int row, int g, bf16x8* af) {
#pragma unroll
    for (int ks = 0; ks < KSTEPS; ++ks)
        af[ks] = *(const bf16x8*)(sA + row * LDA + ks * 32 + g * 8);
}

// B-fragments from fragment-ordered sW: block (n*4+ks) is 1024B, lane reads
// its own contiguous 16B slot. Conflict-free.
template<int KSTEPS>
__device__ inline f32x4 gemm_tileF(const bf16x8* af, const short* sW,
                                   int n, int lane, f32x4 acc) {
#pragma unroll
    for (int ks = 0; ks < KSTEPS; ++ks)
        acc = mfma16(af[ks],
                     *(const bf16x8*)(sW + ((n * 4 + ks) * 64 + lane) * 8), acc);
    return acc;
}

// Weight tile (32KB) global->reg / reg->LDS, lane-linear (conflict-free).
template<int NT>
__device__ inline void loadW(const short* __restrict__ Wsrc, int tid,
                             bf16x8* r) {
    constexpr int P = 2048 / NT;
#pragma unroll
    for (int p = 0; p < P; ++p)
        r[p] = *(const bf16x8*)(Wsrc + (tid + p * NT) * 8);
}
template<int NT>
__device__ inline void writeW(short* sW, int tid, const bf16x8* r) {
    constexpr int P = 2048 / NT;
#pragma unroll
    for (int p = 0; p < P; ++p)
        *(bf16x8*)(sW + (tid + p * NT) * 8) = r[p];
}
template<int NT>
__device__ inline void stageWX(const short* __restrict__ Wsrc, short* sW,
                               int tid) {
    bf16x8 t[2048 / NT];
    loadW<NT>(Wsrc, tid, t);
    writeW<NT>(sW, tid, t);
}

// Stage one wave's 16 rows of a [*,128] f32 matrix into LDS as bf16.
__device__ inline void stage64(const float* __restrict__ gsrc, short* sA,
                               int lane, int rowB) {
    int rr = rowB + (lane >> 2);
    int c0 = (lane & 3) * 32;
    const float* gp = gsrc + (size_t)rr * 128 + c0;
    short* dp = sA + rr * 136 + c0;
#pragma unroll
    for (int p = 0; p < 4; ++p) {
        float4 x = *(const float4*)(gp + p * 8);
        float4 y = *(const float4*)(gp + p * 8 + 4);
        bf16x8 v;
        v[0] = f2bf(x.x); v[1] = f2bf(x.y); v[2] = f2bf(x.z); v[3] = f2bf(x.w);
        v[4] = f2bf(y.x); v[5] = f2bf(y.y); v[6] = f2bf(y.z); v[7] = f2bf(y.w);
        *(bf16x8*)(dp + p * 8) = v;
    }
}

// x1 = LN(eres + A@W + bias); A bf16 in sA, W fragment-ordered in sW.
__device__ inline void proj_ln(short* sA, const f32x4* eres, const short* sW,
                               const float* __restrict__ bias,
                               const float* __restrict__ gma,
                               const float* __restrict__ beta,
                               int rowB, int c, int g, int lane, f32x4* x1v) {
    bf16x8 af[4];
    load_af<4, 136>(sA, rowB + c, g, af);
    float sx[4] = {0, 0, 0, 0}, sxx[4] = {0, 0, 0, 0};
#pragma unroll
    for (int n = 0; n < 8; ++n) {
        f32x4 a = gemm_tileF<4>(af, sW, n, lane, f32x4{0.f, 0.f, 0.f, 0.f});
        const int col = n * 16 + c;
        float bo = bias[col];
#pragma unroll
        for (int r = 0; r < 4; ++r) {
            float xv = a[r] + bo + eres[n][r];
            a[r] = xv; sx[r] += xv; sxx[r] += xv * xv;
        }
        x1v[n] = a;
    }
    float mean[4], inv[4];
#pragma unroll
    for (int r = 0; r < 4; ++r) {
        float s = red16(sx[r]), s2 = red16(sxx[r]);
        mean[r] = s * 0.0078125f;
        float var = s2 * 0.0078125f - mean[r] * mean[r];
        inv[r] = rsqrtf(var + 1e-5f);
    }
#pragma unroll
    for (int n = 0; n < 8; ++n) {
        const int col = n * 16 + c;
        float gg = gma[col], bb = beta[col];
#pragma unroll
        for (int r = 0; r < 4; ++r) {
            float v1 = (x1v[n][r] - mean[r]) * inv[r] * gg + bb;
            x1v[n][r] = v1;
            sA[(rowB + g * 4 + r) * 136 + col] = f2bf(v1);
        }
    }
}

// out = LN(x1 + relu(x1@W1 + b1)@W2 + b2); W1/W2 staged in 32KB halves.
template<int NT>
__device__ inline void ffn_lnS(short* sA, short* sW,
                               const short* __restrict__ W1t,
                               const float* __restrict__ b1,
                               const short* __restrict__ W2t,
                               const float* __restrict__ b2,
                               const float* __restrict__ gma,
                               const float* __restrict__ beta,
                               int rowB, int c, int g, int lane, int tid,
                               f32x4* x1v, float* __restrict__ outp, int tb) {
    bf16x8 af[4];
    load_af<4, 136>(sA, rowB + c, g, af);
    bf16x8 wreg[2048 / NT];
    loadW<NT>(W1t, tid, wreg);
#pragma unroll
    for (int half = 0; half < 2; ++half) {
        __syncthreads();                     // prior sW consumers done
        writeW<NT>(sW, tid, wreg);
        loadW<NT>(W2t + half * 16384, tid, wreg);    // prefetch W2 half
        __syncthreads();
#pragma unroll
        for (int n2 = 0; n2 < 8; ++n2) {
            f32x4 a3 = gemm_tileF<4>(af, sW, n2, lane,
                                     f32x4{0.f, 0.f, 0.f, 0.f});
            const int col2 = half * 128 + n2 * 16 + c;
            float bb = b1[col2];
#pragma unroll
            for (int r = 0; r < 4; ++r)
                sA[(rowB + g * 4 + r) * 136 + n2 * 16 + c] =
                    f2bf(fmaxf(a3[r] + bb, 0.f));
        }
        bf16x8 a4[4];
        load_af<4, 136>(sA, rowB + c, g, a4);
        __syncthreads();
        writeW<NT>(sW, tid, wreg);
        if (half == 0) loadW<NT>(W1t + 16384, tid, wreg);  // prefetch W1 h1
        __syncthreads();
#pragma unroll
        for (int n = 0; n < 8; ++n)
            x1v[n] = gemm_tileF<4>(a4, sW, n, lane, x1v[n]);
    }
    float ty[4] = {0, 0, 0, 0}, tyy[4] = {0, 0, 0, 0};
#pragma unroll
    for (int n = 0; n < 8; ++n) {
        const int col = n * 16 + c;
        float bb = b2[col];
#pragma unroll
        for (int r = 0; r < 4; ++r) {
            float xv = x1v[n][r] + bb;
            x1v[n][r] = xv; ty[r] += xv; tyy[r] += xv * xv;
        }
    }
    float mean[4], inv[4];
#pragma unroll
    for (int r = 0; r < 4; ++r) {
        float s = red16(ty[r]), s2 = red16(tyy[r]);
        mean[r] = s * 0.0078125f;
        float var = s2 * 0.0078125f - mean[r] * mean[r];
        inv[r] = rsqrtf(var + 1e-5f);
    }
#pragma unroll
    for (int n = 0; n < 8; ++n) {
        const int col = n * 16 + c;
        float gg = gma[col], bb = beta[col];
#pragma unroll
        for (int r = 0; r < 4; ++r)
            outp[(size_t)(tb + rowB + g * 4 + r) * 128 + col] =
                (x1v[n][r] - mean[r]) * inv[r] * gg + bb;
    }
}

// ---------------------------------------------------------------- prep
// Emit weights in MFMA fragment order (see gemm_tileF).
__global__ void prep_weights(
    const float* __restrict__ WQ, const float* __restrict__ WK,
    const float* __restrict__ WV, const float* __restrict__ We,
    const float* __restrict__ WOh, const float* __restrict__ WOe,
    const float* __restrict__ Wh1, const float* __restrict__ Wh2,
    const float* __restrict__ We1, const float* __restrict__ We2,
    short* __restrict__ out) {
    int i = blockIdx.x * 256 + threadIdx.x;
    if (i < 98304) {
        int m = i >> 14, r = i & 16383;
        const float* W = m == 0 ? WQ : m == 1 ? WK : m == 2 ? WV
                        : m == 3 ? We : m == 4 ? WOh : WOe;
        int blk = r >> 9, l = (r >> 3) & 63, j = r & 7;
        int n = blk >> 2, ks = blk & 3;
        int col = n * 16 + (l & 15);
        int k = ks * 32 + (l >> 4) * 8 + j;
        out[i] = f2bf(W[k * 128 + col]);
    } else if (i < 229376) {
        int j2 = i - 98304;
        int m = j2 >> 15, r = j2 & 32767;
        int half = r >> 14, q = r & 16383;
        int blk = q >> 9, l = (q >> 3) & 63, j = q & 7;
        int n = blk >> 2, ks = blk & 3;
        if (m == 0 || m == 2) {                    // W1-type [128][256]
            const float* W = (m == 0) ? Wh1 : We1;
            int col2 = half * 128 + n * 16 + (l & 15);
            int k = ks * 32 + (l >> 4) * 8 + j;
            out[i] = f2bf(W[k * 256 + col2]);
        } else {                                   // W2-type [256][128]
            const float* W = (m == 1) ? Wh2 : We2;
            int col = n * 16 + (l & 15);
            int k = half * 128 + ks * 32 + (l >> 4) * 8 + j;
            out[i] = f2bf(W[k * 128 + col]);
        }
    }
}

// ---------------------------------------------------------------- CSR scan
__global__ void __launch_bounds__(1024) scan_kernel(const int* __restrict__ cnt,
                                                    int* __restrict__ off) {
    __shared__ int part[1024];
    int t = threadIdx.x;
    int base = t * 40;
    int s = 0;
    if (base < N_) {
        int end = min(base + 40, N_);
        for (int i = base; i < end; ++i) s += cnt[i];
    }
    part[t] = s;
    __syncthreads();
    for (int d = 1; d < 1024; d <<= 1) {
        int v = (t >= d) ? part[t - d] : 0;
        __syncthreads();
        part[t] += v;
        __syncthreads();
    }
    int prefix = (t == 0) ? 0 : part[t - 1];
    if (base < N_) {
        int end = min(base + 40, N_);
        int run = prefix;
        for (int i = base; i < end; ++i) { off[i] = run; run += cnt[i]; }
    }
    if (t == 1023) off[N_] = part[1023];
}

// ---------------------------------------------------------------- QKV + hist
// Blocks [0,625): QKV projections. Blocks [625,3125): dst histogram.
__global__ void __launch_bounds__(256) qkv_hist_kernel(
    const float* __restrict__ hsrc, const short* __restrict__ Wt3,
    unsigned short* __restrict__ Qo, unsigned short* __restrict__ Ko,
    unsigned short* __restrict__ Vo,
    const int* __restrict__ dst, int* __restrict__ cnt) {
    __shared__ __align__(16) short sA[64 * 136];
    __shared__ __align__(16) short sW[128 * 128];
    const int tid = threadIdx.x;

    if (blockIdx.x >= N_ / 64) {                   // histogram blocks
        int i = (blockIdx.x - N_ / 64) * 256 + tid;
        if (i < E_) atomicAdd(&cnt[dst[i]], 1);
        return;
    }

    const int tb = blockIdx.x * 64;
    const int lane = tid & 63, wave = tid >> 6;
    const int c = lane & 15, g = lane >> 4;
    const int rowB = wave * 16;

    stage64(hsrc + (size_t)tb * 128, sA, lane, rowB);
    bf16x8 af[4];
    load_af<4, 136>(sA, rowB + c, g, af);

    unsigned short* outs[3] = {Qo, Ko, Vo};
#pragma unroll
    for (int w = 0; w < 3; ++w) {
        __syncthreads();
        stageWX<256>(Wt3 + w * 16384, sW, tid);
        __syncthreads();
        unsigned short* op = outs[w];
#pragma unroll
        for (int n = 0; n < 8; ++n) {
            f32x4 a = gemm_tileF<4>(af, sW, n, lane, f32x4{0.f, 0.f, 0.f, 0.f});
            const int col = n * 16 + c;
#pragma unroll
            for (int r = 0; r < 4; ++r)
                op[(size_t)(tb + rowB + g * 4 + r) * 128 + col] =
                    (unsigned short)f2bf(a[r]);
        }
    }
}

// ---------------------------------------------------------------- edges
// 512 threads, 8 waves x 16 edges (M=16), 128 edges/block.
// CSR scatter fused, flat tid<128 form; slots pass through LDS (sSlot).
__global__ void __launch_bounds__(512) edge_kernel(
    const float* __restrict__ e, const int* __restrict__ src,
    const int* __restrict__ dst,
    const int* __restrict__ off, int* __restrict__ cursor,
    int* __restrict__ csr_src,
    const unsigned short* __restrict__ Qb, const unsigned short* __restrict__ Kb,
    float* __restrict__ sexpS,
    const short* __restrict__ Wet, const short* __restrict__ WOet,
    const short* __restrict__ We1t, const short* __restrict__ We2t,
    const float* __restrict__ bOe,
    const float* __restrict__ g1e, const float* __restrict__ b1e,
    const float* __restrict__ be1, const float* __restrict__ be2,
    const float* __restrict__ g2e, const float* __restrict__ b2e,
    float* __restrict__ e2out) {
    __shared__ __align__(16) short sA[128 * 136];  // e -> pe -> score -> x1 -> u
    __shared__ __align__(16) short sW[128 * 128];  // per-phase weight tile
    __shared__ int sSlot[128];                     // CSR slot per edge
    const int tid = threadIdx.x;
    const int tb = blockIdx.x * 128;
    const int lane = tid & 63, wave = tid >> 6;
    const int c = lane & 15, g = lane >> 4;
    const int rowB = wave * 16;

    // fused CSR scatter: flat, no cross-lane ops. One thread per edge.
    if (tid < 128) {
        int d = dst[tb + tid];
        int s = off[d] + atomicAdd(&cursor[d], 1);
        sSlot[tid] = s;
        csr_src[s] = src[tb + tid];
    }

    // preload this wave's 16 src / 16 dst indices (lane-partitioned)
    int pre = 0;
    {
        int li = lane & 15;
        if (lane < 16)       pre = src[tb + rowB + li];
        else if (lane < 32)  pre = dst[tb + rowB + li];
    }

    stageWX<512>(Wet, sW, tid);
    stage64(e + (size_t)tb * 128, sA, lane, rowB);

    // residual e in registers (acc layout), issued early
    f32x4 eres[8];
#pragma unroll
    for (int n = 0; n < 8; ++n)
#pragma unroll
        for (int r = 0; r < 4; ++r)
            eres[n][r] = e[(size_t)(tb + rowB + g * 4 + r) * 128 + n * 16 + c];

    // all 16 K + 16 Q gathers issued before the barrier (drained at it).
    unsigned krg[16], qrg[16];
#pragma unroll
    for (int k = 0; k < 16; ++k) {
        int sI = __shfl(pre, k);
        krg[k] = *(const unsigned*)(Kb + (size_t)sI * 128 + 2 * lane);
    }
#pragma unroll
    for (int k = 0; k < 16; ++k) {
        int dI = __shfl(pre, 16 + k);
        qrg[k] = *(const unsigned*)(Qb + (size_t)dI * 128 + 2 * lane);
    }

    __syncthreads();     // sW(We) + sA + sSlot ready; krg/qrg drained

    // GEMM1: pe = e @ We -> stash bf16 into sA (wave-private rows)
    bf16x8 af[4];
    load_af<4, 136>(sA, rowB + c, g, af);
#pragma unroll
    for (int n = 0; n < 8; ++n) {
        f32x4 p = gemm_tileF<4>(af, sW, n, lane, f32x4{0.f, 0.f, 0.f, 0.f});
#pragma unroll
        for (int r = 0; r < 4; ++r)
            sA[(rowB + g * 4 + r) * 136 + n * 16 + c] = f2bf(p[r]);
    }

    // ---- score phase: consume the prefetched gathers; slot from LDS
    const int head = lane >> 3;
#pragma unroll
    for (int i = 0; i < 16; ++i) {
        const int row = rowB + i;
        const int slot = sSlot[row];            // uniform LDS broadcast
        unsigned kk = krg[i], qq = qrg[i];
        unsigned pp = *(const unsigned*)(sA + row * 136 + 2 * lane);
        float sc0 = bf2f((unsigned short)kk) * bf2f((unsigned short)qq) *
                    0.25f * bf2f((unsigned short)pp);
        float sc1 = bf2f((unsigned short)(kk >> 16)) *
                    bf2f((unsigned short)(qq >> 16)) * 0.25f *
                    bf2f((unsigned short)(pp >> 16));
        *(unsigned*)(sA + row * 136 + 2 * lane) = packbf2(sc0, sc1);
        float s = sc0 + sc1;
        s += __shfl_xor(s, 1);
        s += __shfl_xor(s, 2);
        s += __shfl_xor(s, 4);
        s = fminf(5.f, fmaxf(-5.f, s));
        if ((lane & 7) == 0)
            sexpS[(size_t)slot * 8 + head] = __expf(s);
    }

    __syncthreads();     // all waves done with sW(We)
    stageWX<512>(WOet, sW, tid);
    __syncthreads();

    f32x4 x1v[8];
    proj_ln(sA, eres, sW, bOe, g1e, b1e, rowB, c, g, lane, x1v);
    ffn_lnS<512>(sA, sW, We1t, be1, We2t, be2, g2e, b2e,
                 rowB, c, g, lane, tid, x1v, e2out, tb);
}

// ---------------------------------------------------------------- nodes
__global__ void __launch_bounds__(256) node_kernel(
    const float* __restrict__ h, const unsigned short* __restrict__ Vb,
    const float* __restrict__ sexpS,
    const int* __restrict__ off, const int* __restrict__ csr_src,
    const short* __restrict__ WOht, const short* __restrict__ Wh1t,
    const short* __restrict__ Wh2t,
    const float* __restrict__ bOh,
    const float* __restrict__ g1h, const float* __restrict__ b1h,
    const float* __restrict__ bh1, const float* __restrict__ bh2,
    const float* __restrict__ g2h, const float* __restrict__ b2h,
    float* __restrict__ h2out) {
    __shared__ __align__(16) short sA[64 * 136];
    __shared__ __align__(16) short sW[128 * 128];
    const int tid = threadIdx.x;
    const int tb = blockIdx.x * 64;
    const int lane = tid & 63, wave = tid >> 6;
    const int c = lane & 15, g = lane >> 4;
    const int rowB = wave * 16;
    const int head = lane >> 3;

    stageWX<256>(WOht, sW, tid);     // overlapped with the pull phase

    // residual h in registers (acc layout)
    f32x4 hres[8];
#pragma unroll
    for (int n = 0; n < 8; ++n)
#pragma unroll
        for (int r = 0; r < 4; ++r)
            hres[n][r] = h[(size_t)(tb + rowB + g * 4 + r) * 128 + n * 16 + c];

    // preload CSR offsets for this wave's 16 nodes (+1)
    int offv = (lane < 17) ? off[tb + rowB + lane] : 0;

    // phase A: pull-reduce h_attn, batched 8-wide
    for (int i = 0; i < 16; ++i) {
        const int b0 = __shfl(offv, i), b1 = __shfl(offv, i + 1);
        float a0 = 0.f, a1 = 0.f, zz = 0.f;
        for (int j0 = b0; j0 < b1; j0 += 8) {
            int jj = j0 + (lane & 7);
            int ci = (jj < b1) ? csr_src[jj] : 0;
            unsigned vv[8]; float sv[8];
#pragma unroll
            for (int k = 0; k < 8; ++k) {
                bool ok = (j0 + k) < b1;
                int cs = __shfl(ci, k);
                vv[k] = ok ? *(const unsigned*)(Vb + (size_t)cs * 128 + 2 * lane)
                           : 0u;
                sv[k] = ok ? sexpS[(size_t)(j0 + k) * 8 + head] : 0.f;
            }
#pragma unroll
            for (int k = 0; k < 8; ++k) {
                a0 += bf2f((unsigned short)vv[k]) * sv[k];
                a1 += bf2f((unsigned short)(vv[k] >> 16)) * sv[k];
                zz += sv[k];
            }
        }
        float iz = 1.f / (zz + 1e-6f);
        *(unsigned*)(sA + (rowB + i) * 136 + 2 * lane) = packbf2(a0 * iz, a1 * iz);
    }

    __syncthreads();     // sW(WOh) staged + all sA writes visible

    f32x4 x1v[8];
    proj_ln(sA, hres, sW, bOh, g1h, b1h, rowB, c, g, lane, x1v);
    ffn_lnS<256>(sA, sW, Wh1t, bh1, Wh2t, bh2, g2h, b2h,
                 rowB, c, g, lane, tid, x1v, h2out, tb);
}

// ---------------------------------------------------------------- launch
extern "C" void kernel_launch(void* const* d_in, const int* in_sizes, int n_in,
                              void* d_out, int out_size, void* d_ws,
                              size_t ws_size, hipStream_t stream) {
    const float* h   = (const float*)d_in[0];
    const float* e   = (const float*)d_in[1];
    const int*   src = (const int*)d_in[2];
    const int*   dst = (const int*)d_in[3];
    const float* WQ  = (const float*)d_in[4];
    const float* WK  = (const float*)d_in[5];
    const float* WV  = (const float*)d_in[6];
    const float* We  = (const float*)d_in[7];
    const float* WOh = (const float*)d_in[8];
    const float* bOh = (const float*)d_in[9];
    const float* WOe = (const float*)d_in[10];
    const float* bOe = (const float*)d_in[11];
    const float* g1h = (const float*)d_in[12];
    const float* b1h = (const float*)d_in[13];
    const float* g1e = (const float*)d_in[14];
    const float* b1e = (const float*)d_in[15];
    const float* Wh1 = (const float*)d_in[16];
    const float* bh1 = (const float*)d_in[17];
    const float* Wh2 = (const float*)d_in[18];
    const float* bh2 = (const float*)d_in[19];
    const float* We1 = (const float*)d_in[20];
    const float* be1 = (const float*)d_in[21];
    const float* We2 = (const float*)d_in[22];
    const float* be2 = (const float*)d_in[23];
    const float* g2h = (const float*)d_in[24];
    const float* b2h = (const float*)d_in[25];
    const float* g2e = (const float*)d_in[26];
    const float* b2e = (const float*)d_in[27];

    unsigned short* Qb = (unsigned short*)d_ws;            // N*128 bf16
    unsigned short* Kb = Qb + (size_t)N_ * 128;
    unsigned short* Vb = Kb + (size_t)N_ * 128;
    float* sexpS = (float*)(Vb + (size_t)N_ * 128);        // E*8 (CSR slot order)
    int* cnt     = (int*)(sexpS + (size_t)E_ * 8);         // N
    int* cursor  = cnt + N_;                               // N
    int* off     = cursor + N_;                            // N+1 (pad to N+16)
    int* csr_src = off + N_ + 16;                          // E
    short* Wb    = (short*)(csr_src + E_);                 // bf16 weights (16B-aligned)

    float* h2out = (float*)d_out;
    float* e2out = h2out + (size_t)N_ * 128;

    hipMemsetAsync(cnt, 0, 2 * N_ * sizeof(int), stream);  // cnt + cursor
    prep_weights<<<896, 256, 0, stream>>>(WQ, WK, WV, We, WOh, WOe,
                                          Wh1, Wh2, We1, We2, Wb);
    qkv_hist_kernel<<<N_ / 64 + E_ / 256, 256, 0, stream>>>(
        h, Wb, Qb, Kb, Vb, dst, cnt);
    scan_kernel<<<1, 1024, 0, stream>>>(cnt, off);
    edge_kernel<<<E_ / 128, 512, 0, stream>>>(
        e, src, dst, off, cursor, csr_src, Qb, Kb, sexpS,
        Wb + 3 * 16384, Wb + 5 * 16384,
        Wb + 98304 + 2 * 32768, Wb + 98304 + 3 * 32768,
        bOe, g1e, b1e, be1, be2, g2e, b2e, e2out);
    node_kernel<<<N_ / 64, 256, 0, stream>>>(
        h, Vb, sexpS, off, csr_src,
        Wb + 4 * 16384, Wb + 98304, Wb + 98304 + 32768,
        bOh, g1h, b1h, bh1, bh2, g2h, b2h, h2out);
}